// Round 1
// 345.575 us; speedup vs baseline: 1.1080x; 1.1080x over previous
//
#include <hip/hip_runtime.h>

typedef _Float16 f16;
typedef _Float16 f16x4v __attribute__((ext_vector_type(4)));
typedef _Float16 f16x8 __attribute__((ext_vector_type(8)));
typedef float    f32x4 __attribute__((ext_vector_type(4)));
typedef unsigned int u32;

#define NROWS 65536
#define DDIM  512
#define BM    128     // rows per block = one ghost batch
#define BK    32
#define ZP    516     // zbuf row pitch (floats): 2064 B -> bank-spread reads

// async 16B global->LDS: dest must be wave-uniform base + lane*16.
__device__ __forceinline__ void gload_lds16(const void* g, void* l) {
  __builtin_amdgcn_global_load_lds(
      (const __attribute__((address_space(1))) u32*)g,
      (__attribute__((address_space(3))) u32*)l, 16, 0, 0);
}

__device__ __forceinline__ float wave_sum64(float v) {
  v += __shfl_xor(v, 1);  v += __shfl_xor(v, 2);  v += __shfl_xor(v, 4);
  v += __shfl_xor(v, 8);  v += __shfl_xor(v, 16); v += __shfl_xor(v, 32);
  return v;
}

__device__ __forceinline__ float wave_max64(float v) {
  v = fmaxf(v, __shfl_xor(v, 1));  v = fmaxf(v, __shfl_xor(v, 2));
  v = fmaxf(v, __shfl_xor(v, 4));  v = fmaxf(v, __shfl_xor(v, 8));
  v = fmaxf(v, __shfl_xor(v, 16)); v = fmaxf(v, __shfl_xor(v, 32));
  return v;
}

// ---------------------------------------------------------------------------
// K0: W [k][n] fp32 -> Wt [n][k] f16, k-contiguous, 2-bit chunk XOR-swizzle
// (chunk kp of row n stored at (kp&~3)|((kp&3)^(n&3)) within each 32-k group)
// so the fused kernel's linear global_load_lds lands a conflict-free image.
// ---------------------------------------------------------------------------
__global__ __launch_bounds__(1024) void k_transpose(const float* __restrict__ W,
                                                    f16* __restrict__ Wt) {
  __shared__ float t[32][33];
  const int tx = threadIdx.x, ty = threadIdx.y;
  const int n0 = blockIdx.x * 32, k0 = blockIdx.y * 32;
  t[ty][tx] = W[(size_t)(k0 + ty) * DDIM + n0 + tx];
  __syncthreads();
  const int n = n0 + ty, k = k0 + tx;
  const int kp  = k >> 3;
  const int kps = (kp & ~3) | ((kp & 3) ^ (n & 3));
  Wt[(size_t)n * DDIM + kps * 8 + (k & 7)] = (f16)t[tx][ty];
}

// ---------------------------------------------------------------------------
// K1: fully fused  out = sparsemax( ghostBN(A @ W) * priors ).
// Block: 128 rows x 512 cols (BN stats AND sparsemax rows complete in-block).
// 1024 threads = 16 waves; wave tile 128x32 -> column stats in-wave (2 shfl).
// K-loop: f16 MFMA 16x16x32, A staged with inline fp32->f16 convert (read
// once, no cast kernel), B via global_load_lds from pre-swizzled Wt.
// Epilogue: 8 passes of 16 rows through f32 LDS transpose buffer; priors/out
// accessed as fully-coalesced float4 rows; wave-per-row monotone Michelot
// with (a) tau0 = rowmax-1 (provable lower bound on tau*, collapses the
// initial support from 512 to ~a handful -> ~3-5 iterations) and (b) the
// support count via __ballot+popcount on the SALU (no float count-reduce,
// uniform scalar convergence branch).
// ---------------------------------------------------------------------------
__global__ __launch_bounds__(1024, 4) void k_fused(
    const float* __restrict__ A, const float* __restrict__ priors,
    const f16*  __restrict__ Bt, const float* __restrict__ gamma,
    const float* __restrict__ beta, float* __restrict__ Out) {
  __shared__ __align__(16) char smem[40960];
  f16*   Al = (f16*)smem;              // [128][32] = 8 KB  (staging)
  f16*   Bl = (f16*)(smem + 8192);     // [512][32] = 32 KB (staging)
  float* zb = (float*)smem;            // [16][516] = 33 KB (epilogue, reuses)

  const int tid  = threadIdx.x;
  const int lane = tid & 63;
  const int wid  = tid >> 6;           // 0..15: wave = 32-col slice
  const int lr   = lane & 15;
  const int lq   = lane >> 4;
  const int m0   = blockIdx.x * BM;

  // A staging map: thread -> (row, 4-float half-chunk), swizzled LDS dest
  const int arow = tid >> 3;           // 0..127
  const int aq   = tid & 7;            // half-chunk (4 floats)
  const int akps = (aq >> 1) ^ (arow & 3);
  const float* ap = A + (size_t)(m0 + arow) * DDIM + aq * 4;
  f16* adst = Al + arow * BK + akps * 8 + (aq & 1) * 4;

  f32x4 acc[8][2];
#pragma unroll
  for (int mi = 0; mi < 8; ++mi)
#pragma unroll
    for (int ni = 0; ni < 2; ++ni) acc[mi][ni] = (f32x4){0.f, 0.f, 0.f, 0.f};

  for (int ks = 0; ks < DDIM / BK; ++ks) {   // 16 K-steps
    const int kb = ks * BK;
    // B: 512 cols x 32 k = 2048 x 16B chunks, 2/thread, async DMA
#pragma unroll
    for (int r = 0; r < 2; ++r) {
      const int c = tid + r * 1024;
      const int col = c >> 2, kp = c & 3;
      gload_lds16(Bt + (size_t)col * DDIM + kb + kp * 8, (char*)Bl + c * 16);
    }
    // A: fp32 float4 -> f16x4, swizzled ds_write
    const float4 av = *(const float4*)(ap + kb);
    f16x4v hv = {(f16)av.x, (f16)av.y, (f16)av.z, (f16)av.w};
    *(f16x4v*)adst = hv;
    __syncthreads();

    const int cs = lq ^ (lr & 3);            // de-swizzle chunk select
    const f16x8 bf0 = *(const f16x8*)(Bl + (size_t)(wid * 32 + lr) * BK + cs * 8);
    const f16x8 bf1 = *(const f16x8*)(Bl + (size_t)(wid * 32 + 16 + lr) * BK + cs * 8);
#pragma unroll
    for (int mi = 0; mi < 8; ++mi) {
      const f16x8 af = *(const f16x8*)(Al + (size_t)(mi * 16 + lr) * BK + cs * 8);
      acc[mi][0] = __builtin_amdgcn_mfma_f32_16x16x32_f16(af, bf0, acc[mi][0], 0, 0, 0);
      acc[mi][1] = __builtin_amdgcn_mfma_f32_16x16x32_f16(af, bf1, acc[mi][1], 0, 0, 0);
    }
    __syncthreads();
  }

  // --- ghost-BN stats in-wave (wave owns whole columns) + apply ---
  // C/D layout: col = lane&15 (per 16-tile), row = mi*16 + lq*4 + r
#pragma unroll
  for (int ni = 0; ni < 2; ++ni) {
    float ps = 0.f, pq = 0.f;
#pragma unroll
    for (int mi = 0; mi < 8; ++mi)
#pragma unroll
      for (int r = 0; r < 4; ++r) {
        const float v = acc[mi][ni][r];
        ps += v; pq += v * v;
      }
    ps += __shfl_xor(ps, 16); ps += __shfl_xor(ps, 32);  // sum over lq
    pq += __shfl_xor(pq, 16); pq += __shfl_xor(pq, 32);
    const int col = wid * 32 + ni * 16 + lr;
    const float mean = ps * (1.f / 128.f);
    const float var  = pq * (1.f / 128.f) - mean * mean;
    const float rstd = rsqrtf(var + 1e-3f);
    const float s = rstd * gamma[col];
    const float b = beta[col] - mean * s;
#pragma unroll
    for (int mi = 0; mi < 8; ++mi)
#pragma unroll
      for (int r = 0; r < 4; ++r)
        acc[mi][ni][r] = acc[mi][ni][r] * s + b;
  }

  // --- epilogue: 8 passes x 16 rows; LDS transpose -> coalesced sparsemax ---
#pragma unroll
  for (int p = 0; p < 8; ++p) {
    __syncthreads();                         // zb free (prev pass / staging)
    // dump rows p*16..p*16+15 (mi = p): 2-way-max bank aliasing (free)
#pragma unroll
    for (int ni = 0; ni < 2; ++ni)
#pragma unroll
      for (int r = 0; r < 4; ++r)
        zb[(lq * 4 + r) * ZP + wid * 32 + ni * 16 + lr] = acc[p][ni][r];
    __syncthreads();

    // wave `wid` processes local row `wid`: 8 f32/lane, fully coalesced I/O
    const int grow = m0 + p * 16 + wid;
    const float* pr = priors + (size_t)grow * DDIM;
    float* orow = Out + (size_t)grow * DDIM;
    float z[8];
    float M = -1e30f;
#pragma unroll
    for (int k = 0; k < 2; ++k) {
      const int cc = (lane + 64 * k) * 4;
      const float4 zv = *(const float4*)(zb + wid * ZP + cc);
      const float4 pv = *(const float4*)(pr + cc);
      z[4 * k]     = zv.x * pv.x; z[4 * k + 1] = zv.y * pv.y;
      z[4 * k + 2] = zv.z * pv.z; z[4 * k + 3] = zv.w * pv.w;
      M = fmaxf(M, fmaxf(fmaxf(z[4 * k], z[4 * k + 1]),
                         fmaxf(z[4 * k + 2], z[4 * k + 3])));
    }
    // tau* >= zmax - 1 (since sum of (z - tau*)+ = 1 bounds zmax - tau* <= 1),
    // and Michelot from any tau0 <= tau* keeps support ⊇ support* -> monotone.
    M = wave_max64(M);
    float tau = M - 1.f;
    unsigned rcprev = 0xFFFFFFFFu;
    for (int it = 0; it < 40; ++it) {        // converges in ~3-5 iters
      float rs = 0.f;
      unsigned rc = 0;
#pragma unroll
      for (int j = 0; j < 8; ++j) {
        const bool a = z[j] > tau;
        rs += a ? z[j] : 0.f;
        rc += (unsigned)__popcll(__ballot(a));  // SALU count, no shuffles
        z[j] = a ? z[j] : -1e30f;               // knock out, never re-admit
      }
      rs = wave_sum64(rs);
      if (rc == rcprev) break;                  // uniform scalar branch
      rcprev = rc;
      tau = (rs - 1.f) / (float)rc;             // rc >= 1 (max survives)
    }
#pragma unroll
    for (int k = 0; k < 2; ++k) {
      const int cc = (lane + 64 * k) * 4;
      float4 o;
      o.x = fmaxf(z[4 * k]     - tau, 0.f);
      o.y = fmaxf(z[4 * k + 1] - tau, 0.f);
      o.z = fmaxf(z[4 * k + 2] - tau, 0.f);
      o.w = fmaxf(z[4 * k + 3] - tau, 0.f);
      *(float4*)(orow + cc) = o;
    }
  }
}

// ---------------------------------------------------------------------------
extern "C" void kernel_launch(void* const* d_in, const int* in_sizes, int n_in,
                              void* d_out, int out_size, void* d_ws, size_t ws_size,
                              hipStream_t stream) {
  const float* inputs = (const float*)d_in[0];
  const float* priors = (const float*)d_in[1];
  const float* W      = (const float*)d_in[2];
  const float* gamma  = (const float*)d_in[3];
  const float* beta   = (const float*)d_in[4];
  float* out = (float*)d_out;
  f16*   Wt  = (f16*)d_ws;                   // 512 KB scratch

  hipLaunchKernelGGL(k_transpose, dim3(DDIM / 32, DDIM / 32), dim3(32, 32), 0, stream, W, Wt);
  hipLaunchKernelGGL(k_fused, dim3(NROWS / BM), dim3(1024), 0, stream,
                     inputs, priors, Wt, gamma, beta, out);
}

// Round 2
// 345.480 us; speedup vs baseline: 1.1083x; 1.0003x over previous
//
#include <hip/hip_runtime.h>

typedef _Float16 f16;
typedef _Float16 f16x4v __attribute__((ext_vector_type(4)));
typedef _Float16 f16x8 __attribute__((ext_vector_type(8)));
typedef float    f32x4 __attribute__((ext_vector_type(4)));
typedef unsigned int u32;

#define NROWS 65536
#define DDIM  512
#define BM    128     // rows per block = one ghost batch
#define BK    32
#define ZP    516     // zbuf row pitch (floats): 2064 B -> bank-spread reads

// async 16B global->LDS: dest must be wave-uniform base + lane*16.
__device__ __forceinline__ void gload_lds16(const void* g, void* l) {
  __builtin_amdgcn_global_load_lds(
      (const __attribute__((address_space(1))) u32*)g,
      (__attribute__((address_space(3))) u32*)l, 16, 0, 0);
}

// ---- DPP wave-64 reductions: ~10x shorter dependent chain than ds_swizzle --
template <int CTRL, int RM>
__device__ __forceinline__ float dpp_mov_f(float src, float old) {
  return __int_as_float(__builtin_amdgcn_update_dpp(
      __float_as_int(old), __float_as_int(src), CTRL, RM, 0xf, false));
}
// full-wave sum, result broadcast (uniform) via readlane 63
__device__ __forceinline__ float dpp_sum64(float x) {
  x += dpp_mov_f<0x121, 0xf>(x, 0.f);   // row_ror:1
  x += dpp_mov_f<0x122, 0xf>(x, 0.f);   // row_ror:2
  x += dpp_mov_f<0x124, 0xf>(x, 0.f);   // row_ror:4
  x += dpp_mov_f<0x128, 0xf>(x, 0.f);   // row_ror:8  -> each lane: row sum
  x += dpp_mov_f<0x142, 0xa>(x, 0.f);   // bcast15 -> rows 1,3
  x += dpp_mov_f<0x143, 0xc>(x, 0.f);   // bcast31 -> rows 2,3 (lane63 = total)
  return __int_as_float(__builtin_amdgcn_readlane(__float_as_int(x), 63));
}
__device__ __forceinline__ float dpp_max64(float x) {
  x = fmaxf(x, dpp_mov_f<0x121, 0xf>(x, -1e30f));
  x = fmaxf(x, dpp_mov_f<0x122, 0xf>(x, -1e30f));
  x = fmaxf(x, dpp_mov_f<0x124, 0xf>(x, -1e30f));
  x = fmaxf(x, dpp_mov_f<0x128, 0xf>(x, -1e30f));
  x = fmaxf(x, dpp_mov_f<0x142, 0xa>(x, -1e30f));
  x = fmaxf(x, dpp_mov_f<0x143, 0xc>(x, -1e30f));
  return __int_as_float(__builtin_amdgcn_readlane(__float_as_int(x), 63));
}

// ---------------------------------------------------------------------------
// K0: W [k][n] fp32 -> Wt [n][k] f16, k-contiguous, 2-bit chunk XOR-swizzle
// so the fused kernel's linear global_load_lds lands a conflict-free image.
// ---------------------------------------------------------------------------
__global__ __launch_bounds__(1024) void k_transpose(const float* __restrict__ W,
                                                    f16* __restrict__ Wt) {
  __shared__ float t[32][33];
  const int tx = threadIdx.x, ty = threadIdx.y;
  const int n0 = blockIdx.x * 32, k0 = blockIdx.y * 32;
  t[ty][tx] = W[(size_t)(k0 + ty) * DDIM + n0 + tx];
  __syncthreads();
  const int n = n0 + ty, k = k0 + tx;
  const int kp  = k >> 3;
  const int kps = (kp & ~3) | ((kp & 3) ^ (n & 3));
  Wt[(size_t)n * DDIM + kps * 8 + (k & 7)] = (f16)t[tx][ty];
}

// ---------------------------------------------------------------------------
// K1: fully fused  out = sparsemax( ghostBN(A @ W) * priors ).
// 1 block/CU (reg-capped: 64 AGPR acc + ~60 VGPR = 4 waves/SIMD), so the
// kernel is latency-bound -> this version hides latency instead of adding TLP:
//  * K-loop: double-buffered LDS (A 2x8KB, B 2x32KB), B gloads issued for
//    tile k+1 BEFORE computing tile k, A register-prefetched 2 tiles ahead;
//    ONE barrier per K-step (was 2, with zero-overlap drain).
//  * Epilogue: DPP reductions (row_ror + bcast, ~60cyc chain vs ~600 for
//    ds_swizzle shuffles), priors hoisted above the pass barrier, zb double-
//    buffered -> ONE barrier per pass.
// ---------------------------------------------------------------------------
__global__ __launch_bounds__(1024, 4) void k_fused(
    const float* __restrict__ A, const float* __restrict__ priors,
    const f16*  __restrict__ Bt, const float* __restrict__ gamma,
    const float* __restrict__ beta, float* __restrict__ Out) {
  __shared__ __align__(16) char smem[81920];
  f16*  Al0 = (f16*)smem;               // [128][32] f16 = 8 KB
  f16*  Al1 = (f16*)(smem + 8192);      // 8 KB
  char* Bs0 = smem + 16384;             // [512][32] f16 = 32 KB
  char* Bs1 = smem + 49152;             // 32 KB
  float* zb0 = (float*)smem;            // [16][516] f32 = 33 KB (epilogue)
  float* zb1 = (float*)(smem + 33024);  // 33 KB (overlays staging; barriered)

  const int tid  = threadIdx.x;
  const int lane = tid & 63;
  const int wid  = tid >> 6;           // 0..15: wave = 32-col slice
  const int lr   = lane & 15;
  const int lq   = lane >> 4;
  const int m0   = blockIdx.x * BM;

  // A staging map: thread -> (row, 4-float half-chunk), swizzled LDS dest
  const int arow = tid >> 3;           // 0..127
  const int aq   = tid & 7;            // half-chunk (4 floats)
  const int akps = (aq >> 1) ^ (arow & 3);
  const float* ap = A + (size_t)(m0 + arow) * DDIM + aq * 4;
  const int adoff = arow * BK + akps * 8 + (aq & 1) * 4;  // f16 elems

  // B staging map: 2 x 16B chunks per thread
  const int c0 = tid, c1 = tid + 1024;
  const f16* bsrc0 = Bt + (size_t)(c0 >> 2) * DDIM + (c0 & 3) * 8;
  const f16* bsrc1 = Bt + (size_t)(c1 >> 2) * DDIM + (c1 & 3) * 8;

  f32x4 acc[8][2];
#pragma unroll
  for (int mi = 0; mi < 8; ++mi)
#pragma unroll
    for (int ni = 0; ni < 2; ++ni) acc[mi][ni] = (f32x4){0.f, 0.f, 0.f, 0.f};

  const int cs = lq ^ (lr & 3);        // de-swizzle chunk select

  // ---- prologue: tile 0 staged to buf0; A tile 1 register-prefetched ----
  {
    const float4 av0 = *(const float4*)(ap);
    gload_lds16(bsrc0, Bs0 + (size_t)c0 * 16);
    gload_lds16(bsrc1, Bs0 + (size_t)c1 * 16);
    f16x4v hv = {(f16)av0.x, (f16)av0.y, (f16)av0.z, (f16)av0.w};
    *(f16x4v*)(Al0 + adoff) = hv;      // compiler waits av0 only
  }
  float4 avA = *(const float4*)(ap + BK);   // tile 1, in flight across step 0
  __syncthreads();

  f16*  AlC = Al0; f16*  AlN = Al1;
  char* BsC = Bs0; char* BsN = Bs1;

#pragma unroll 2
  for (int ks = 0; ks < 15; ++ks) {
    // issue tile ks+1 B loads into the idle buffer (latency hides under MFMA)
    const int kb1 = (ks + 1) * BK;
    gload_lds16(bsrc0 + kb1, BsN + (size_t)c0 * 16);
    gload_lds16(bsrc1 + kb1, BsN + (size_t)c1 * 16);
    // issue A tile ks+2 (2-deep register prefetch)
    float4 avn;
    if (ks < 14) avn = *(const float4*)(ap + (ks + 2) * BK);

    // compute tile ks from current buffers
    const f16* Blc = (const f16*)BsC;
    const f16x8 bf0 = *(const f16x8*)(Blc + (size_t)(wid * 32 + lr) * BK + cs * 8);
    const f16x8 bf1 = *(const f16x8*)(Blc + (size_t)(wid * 32 + 16 + lr) * BK + cs * 8);
#pragma unroll
    for (int mi = 0; mi < 8; ++mi) {
      const f16x8 af = *(const f16x8*)(AlC + (size_t)(mi * 16 + lr) * BK + cs * 8);
      acc[mi][0] = __builtin_amdgcn_mfma_f32_16x16x32_f16(af, bf0, acc[mi][0], 0, 0, 0);
      acc[mi][1] = __builtin_amdgcn_mfma_f32_16x16x32_f16(af, bf1, acc[mi][1], 0, 0, 0);
    }

    // stage A tile ks+1 (avA loaded 2 steps ago -> latency fully covered)
    f16x4v hv = {(f16)avA.x, (f16)avA.y, (f16)avA.z, (f16)avA.w};
    *(f16x4v*)(AlN + adoff) = hv;
    avA = avn;

    { f16* t = AlC; AlC = AlN; AlN = t; }
    { char* t = BsC; BsC = BsN; BsN = t; }
    __syncthreads();                   // single barrier per K-step
  }
  // final tile 15 (no staging)
  {
    const f16* Blc = (const f16*)BsC;
    const f16x8 bf0 = *(const f16x8*)(Blc + (size_t)(wid * 32 + lr) * BK + cs * 8);
    const f16x8 bf1 = *(const f16x8*)(Blc + (size_t)(wid * 32 + 16 + lr) * BK + cs * 8);
#pragma unroll
    for (int mi = 0; mi < 8; ++mi) {
      const f16x8 af = *(const f16x8*)(AlC + (size_t)(mi * 16 + lr) * BK + cs * 8);
      acc[mi][0] = __builtin_amdgcn_mfma_f32_16x16x32_f16(af, bf0, acc[mi][0], 0, 0, 0);
      acc[mi][1] = __builtin_amdgcn_mfma_f32_16x16x32_f16(af, bf1, acc[mi][1], 0, 0, 0);
    }
  }

  // --- ghost-BN stats in-wave (wave owns whole columns) + apply ---
  // C/D layout: col = lane&15 (per 16-tile), row = mi*16 + lq*4 + r
#pragma unroll
  for (int ni = 0; ni < 2; ++ni) {
    float ps = 0.f, pq = 0.f;
#pragma unroll
    for (int mi = 0; mi < 8; ++mi)
#pragma unroll
      for (int r = 0; r < 4; ++r) {
        const float v = acc[mi][ni][r];
        ps += v; pq += v * v;
      }
    ps += __shfl_xor(ps, 16); ps += __shfl_xor(ps, 32);  // sum over lq
    pq += __shfl_xor(pq, 16); pq += __shfl_xor(pq, 32);
    const int col = wid * 32 + ni * 16 + lr;
    const float mean = ps * (1.f / 128.f);
    const float var  = pq * (1.f / 128.f) - mean * mean;
    const float rstd = rsqrtf(var + 1e-3f);
    const float s = rstd * gamma[col];
    const float b = beta[col] - mean * s;
#pragma unroll
    for (int mi = 0; mi < 8; ++mi)
#pragma unroll
      for (int r = 0; r < 4; ++r)
        acc[mi][ni][r] = acc[mi][ni][r] * s + b;
  }

  __syncthreads();   // staging LDS reads done everywhere -> zb may overlay

  // --- epilogue: 8 passes x 16 rows; dbuf LDS transpose, 1 barrier/pass ---
  const float* pr_base = priors + (size_t)(m0 + wid) * DDIM;
  float* out_base = Out + (size_t)(m0 + wid) * DDIM;
#pragma unroll
  for (int p = 0; p < 8; ++p) {
    float* zbc = (p & 1) ? zb1 : zb0;
    // dump rows p*16..p*16+15 (mi = p): 2-way-max bank aliasing (free)
#pragma unroll
    for (int ni = 0; ni < 2; ++ni)
#pragma unroll
      for (int r = 0; r < 4; ++r)
        zbc[(lq * 4 + r) * ZP + wid * 32 + ni * 16 + lr] = acc[p][ni][r];

    // hoist priors (HBM ~900cyc) above the barrier: hides under write+wait
    const float* pr = pr_base + (size_t)p * 16 * DDIM;
    const float4 pva = *(const float4*)(pr + lane * 4);
    const float4 pvb = *(const float4*)(pr + 256 + lane * 4);
    __syncthreads();

    // wave `wid` processes local row `wid`: 8 f32/lane, fully coalesced I/O
    const float4 zva = *(const float4*)(zbc + wid * ZP + lane * 4);
    const float4 zvb = *(const float4*)(zbc + wid * ZP + 256 + lane * 4);
    float z[8];
    z[0] = zva.x * pva.x; z[1] = zva.y * pva.y;
    z[2] = zva.z * pva.z; z[3] = zva.w * pva.w;
    z[4] = zvb.x * pvb.x; z[5] = zvb.y * pvb.y;
    z[6] = zvb.z * pvb.z; z[7] = zvb.w * pvb.w;
    float M = fmaxf(fmaxf(fmaxf(z[0], z[1]), fmaxf(z[2], z[3])),
                    fmaxf(fmaxf(z[4], z[5]), fmaxf(z[6], z[7])));
    // tau* >= zmax - 1; Michelot from tau0 <= tau* is monotone-correct.
    M = dpp_max64(M);
    float tau = M - 1.f;
    unsigned rcprev = 0xFFFFFFFFu;
    for (int it = 0; it < 40; ++it) {        // converges in ~3-5 iters
      float rs = 0.f;
      unsigned rc = 0;
#pragma unroll
      for (int j = 0; j < 8; ++j) {
        const bool a = z[j] > tau;
        rs += a ? z[j] : 0.f;
        rc += (unsigned)__popcll(__ballot(a));  // SALU count
        z[j] = a ? z[j] : -1e30f;               // knock out, never re-admit
      }
      rs = dpp_sum64(rs);                       // ~60cyc chain, uniform result
      if (rc == rcprev) break;                  // uniform scalar branch
      rcprev = rc;
      tau = (rs - 1.f) / (float)rc;             // rc >= 1 (max survives)
    }
    float* orow = out_base + (size_t)p * 16 * DDIM;
    float4 o;
    o.x = fmaxf(z[0] - tau, 0.f); o.y = fmaxf(z[1] - tau, 0.f);
    o.z = fmaxf(z[2] - tau, 0.f); o.w = fmaxf(z[3] - tau, 0.f);
    *(float4*)(orow + lane * 4) = o;
    o.x = fmaxf(z[4] - tau, 0.f); o.y = fmaxf(z[5] - tau, 0.f);
    o.z = fmaxf(z[6] - tau, 0.f); o.w = fmaxf(z[7] - tau, 0.f);
    *(float4*)(orow + 256 + lane * 4) = o;
  }
}

// ---------------------------------------------------------------------------
extern "C" void kernel_launch(void* const* d_in, const int* in_sizes, int n_in,
                              void* d_out, int out_size, void* d_ws, size_t ws_size,
                              hipStream_t stream) {
  const float* inputs = (const float*)d_in[0];
  const float* priors = (const float*)d_in[1];
  const float* W      = (const float*)d_in[2];
  const float* gamma  = (const float*)d_in[3];
  const float* beta   = (const float*)d_in[4];
  float* out = (float*)d_out;
  f16*   Wt  = (f16*)d_ws;                   // 512 KB scratch

  hipLaunchKernelGGL(k_transpose, dim3(DDIM / 32, DDIM / 32), dim3(32, 32), 0, stream, W, Wt);
  hipLaunchKernelGGL(k_fused, dim3(NROWS / BM), dim3(1024), 0, stream,
                     inputs, priors, Wt, gamma, beta, out);
}